// Round 3
// baseline (226.296 us; speedup 1.0000x reference)
//
#include <hip/hip_runtime.h>
#include <stdint.h>

#define N_ROWS 4096
#define DIM    1024
#define NCLS   64
#define EPSV   0.1f

typedef __attribute__((ext_vector_type(4))) float f32x4;
typedef __attribute__((ext_vector_type(4))) int   i32x4;
typedef __attribute__((ext_vector_type(8))) int   i32x8;

__device__ __forceinline__ void async_cp16(const void* g, void* l) {
    __builtin_amdgcn_global_load_lds((const __attribute__((address_space(1))) void*)g,
                                     (__attribute__((address_space(3))) void*)l,
                                     16, 0, 0);
}

__device__ __forceinline__ float softplus(float x) {
    return fmaxf(x, 0.f) + __logf(1.f + __expf(-fabsf(x)));
}

// ---------------- K1: per-class sum/sqsum via row gather (unchanged) ---------
__global__ __launch_bounds__(256) void k_cstats(const float* __restrict__ X,
                                                const int* __restrict__ tgt,
                                                float* __restrict__ csumR,
                                                float* __restrict__ csqR) {
    __shared__ int rows[N_ROWS];
    __shared__ int nrows_s;
    int tid = threadIdx.x;
    int c = blockIdx.x >> 2, q = blockIdx.x & 3;
    if (tid == 0) nrows_s = 0;
    __syncthreads();
    for (int i = tid; i < N_ROWS; i += 256)
        if (tgt[i] == c) { int p = atomicAdd(&nrows_s, 1); rows[p] = i; }
    __syncthreads();
    int n = nrows_s;
    int d = q * 256 + tid;
    float s = 0.f, qq = 0.f;
    #pragma unroll 4
    for (int r = 0; r < n; r++) {
        float x = X[(size_t)rows[r] * DIM + d];
        s += x; qq += x * x;
    }
    csumR[c * DIM + d] = s;
    csqR [c * DIM + d] = qq;
}

// ---------------- K2: counts + weights + fp8 scale + zero loss (unchanged) ---
__global__ __launch_bounds__(128) void k_weights(const int* __restrict__ tgt,
                                                 const float* __restrict__ csumR,
                                                 const float* __restrict__ csqR,
                                                 float* __restrict__ w,
                                                 float* __restrict__ scal,
                                                 float* __restrict__ loss_out) {
    __shared__ int hist[NCLS];
    __shared__ float redw[2];
    int tid = threadIdx.x, b = blockIdx.x;
    if (tid < NCLS) hist[tid] = 0;
    __syncthreads();
    for (int i = tid; i < N_ROWS; i += 128) atomicAdd(&hist[tgt[i]], 1);
    __syncthreads();
    long long sp = 0, ss = 0;
    for (int c = 0; c < NCLS; c++) { long long cc = hist[c]; sp += cc * (cc - 1); ss += cc * cc; }
    float cnt_pos = (float)sp;
    float cnt_neg = (float)((long long)N_ROWS * N_ROWS - ss);
    int d = b * 128 + tid;
    float A = 0.f, X2 = 0.f, T = 0.f, SS = 0.f;
    #pragma unroll 8
    for (int c = 0; c < NCLS; c++) {
        float s = csumR[c * DIM + d];
        float q = csqR [c * DIM + d];
        A += (float)hist[c] * q; X2 += q; T += s; SS += s * s;
    }
    float posnum = 2.f * (A - SS);
    float negnum = 2.f * ((float)N_ROWS * X2 - A - T * T + SS);
    float wd = cnt_neg / (negnum + EPSV) - cnt_pos / (posnum + EPSV);
    w[d] = wd;
    float m = wd * wd;
    for (int off = 32; off; off >>= 1) m += __shfl_down(m, off, 64);
    int wv = tid >> 6, ln = tid & 63;
    if (ln == 0) redw[wv] = m;
    __syncthreads();
    if (b == 0 && tid == 0) {
        float ms = (redw[0] + redw[1]) / 128.f;
        scal[0] = exp2f(roundf(log2f(sqrtf(ms) + 1e-30f)));
        loss_out[0] = 0.0f;
    }
}

// ---------------- K3: xw, sq (fp32 exact), fp8 casts, PLAIN row-major --------
// Swizzle is baked into the MX gemm's global source addresses instead
// (global_load_lds writes linearly, rule #21).
__global__ __launch_bounds__(256) void k_prep(const float* __restrict__ X,
                                              const float* __restrict__ w,
                                              const float* __restrict__ scal,
                                              unsigned int* __restrict__ Xb8,
                                              unsigned int* __restrict__ XWb8,
                                              float* __restrict__ sq) {
    int row = blockIdx.x, tid = threadIdx.x;
    float inv_sw = 1.0f / scal[0];
    float4 x  = ((const float4*)(X + (size_t)row * DIM))[tid];
    float4 ww = ((const float4*)w)[tid];
    float4 xw = make_float4(x.x * ww.x, x.y * ww.y, x.z * ww.z, x.w * ww.w);
    float p = x.x * xw.x + x.y * xw.y + x.z * xw.z + x.w * xw.w;
    unsigned ux = __builtin_amdgcn_cvt_pk_fp8_f32(x.x, x.y, 0, false);
    ux = __builtin_amdgcn_cvt_pk_fp8_f32(x.z, x.w, ux, true);
    unsigned uw = __builtin_amdgcn_cvt_pk_fp8_f32(xw.x * inv_sw, xw.y * inv_sw, 0, false);
    uw = __builtin_amdgcn_cvt_pk_fp8_f32(xw.z * inv_sw, xw.w * inv_sw, uw, true);
    int widx = row * 256 + tid;            // plain row-major fp8
    Xb8 [widx] = ux;
    XWb8[widx] = uw;
    for (int off = 32; off; off >>= 1) p += __shfl_down(p, off, 64);
    __shared__ float red[4];
    int wv = tid >> 6, ln = tid & 63;
    if (ln == 0) red[wv] = p;
    __syncthreads();
    if (tid == 0) sq[row] = red[0] + red[1] + red[2] + red[3];
}

// ---------------- K4: MX-fp8 (scale=1) MFMA gram + softplus + masked mean ----
// mfma_scale_f32_16x16x128_f8f6f4, E8M0 scale 127 (=1.0): bit-identical fp8
// products at 2x the non-scaled fp8 issue rate. Operand/C layouts already
// harness-verified (R1/R2 absmax = 0.0).
// GEOMETRY CHANGE vs R2: 512 thr = 8 waves (2x4), wave tile 64x32 (4x2 16x16
// frags). R2's 4-wave 64x64 config demanded >256 VGPRs (acc 64 + aligned
// 8-reg operand tuples) -> VGPR_Count pinned at the 256 arch max + 49 MB
// scratch each way. This config: acc[4][2]=32 + bv[2]=16 + av=8 ~ 110-130
// VGPRs -> no spill, ~4 waves/SIMD.
// Staging: waves 0-3 -> A slab, waves 4-7 -> B slab; 4 x 16 B issues per
// thread per K-step; LDS linear dest, granule swizzle baked into global src
// (phys16B = logical16B ^ (row&7)); single-buffered 2-barrier loop.
__global__ __launch_bounds__(512) void k_gemm_loss(const unsigned char* __restrict__ Xb8,
                                                   const unsigned char* __restrict__ XWb8,
                                                   const float* __restrict__ sq,
                                                   const int* __restrict__ tgt,
                                                   const float* __restrict__ scal,
                                                   float* __restrict__ loss) {
    __shared__ __align__(16) unsigned char As[16384];   // 128 rows x 128 B (one K-step)
    __shared__ __align__(16) unsigned char Bs[16384];
    __shared__ float sqI[128], sqJ[128];
    __shared__ int   tIs[128], tJs[128];
    __shared__ float red[8];

    int tid = threadIdx.x;
    int wave = tid >> 6, lane = tid & 63;

    // balanced triangular decode (32x32 tile grid, 528 tiles)
    int g = blockIdx.x & 7, s = blockIdx.x >> 3;
    int j0 = g, j1 = 15 - g, j2 = 16 + g;
    int n0 = j0 + 1, n1 = j1 + 1, n2 = j2 + 1;
    int jt, it;
    if      (s < n0)           { jt = j0; it = s; }
    else if (s < n0 + n1)      { jt = j1; it = s - n0; }
    else if (s < n0 + n1 + n2) { jt = j2; it = s - n0 - n1; }
    else                       { jt = 31 - g; it = s - n0 - n1 - n2; }

    // staging: waves 0-3 stage A, waves 4-7 stage B. Per K-step each thread
    // issues 4 x 16 B. Issue i covers LDS rows i*32..i*32+31; thread ch =
    // (wave&3)*64+lane -> row i*32 + (ch>>3), phys granule ch&7; global src
    // holds logical granule (ch&7) ^ (row&7).
    bool isA = wave < 4;
    const unsigned char* srcb = (isA ? Xb8 : XWb8) + (size_t)((isA ? it : jt) * 128) * DIM;
    unsigned char* slab = isA ? As : Bs;
    int ch = (wave & 3) * 64 + lane;
    const unsigned char* gp[4];
    int ldo[4];
    #pragma unroll
    for (int i = 0; i < 4; i++) {
        int r  = i * 32 + (ch >> 3);
        int pg = ch & 7;
        gp[i]  = srcb + (size_t)r * DIM + (size_t)((pg ^ (r & 7)) << 4);
        ldo[i] = i * 4096 + (wave & 3) * 1024;   // wave-uniform; dest = +lane*16
    }

    // fragment LDS byte offsets (step-invariant, single buffer)
    int lr = lane & 15, hk = lane >> 4;          // hk = K 32B-group
    int wrow = (wave >> 2) * 64, wcol = (wave & 3) * 32;
    int offA[4], offB[2];
    #pragma unroll
    for (int mi = 0; mi < 4; mi++) {
        int r = wrow + mi * 16 + lr;
        offA[mi] = r * 128 + (((hk * 2) ^ (r & 7)) << 4);
    }
    #pragma unroll
    for (int nj = 0; nj < 2; nj++) {
        int c = wcol + nj * 16 + lr;
        offB[nj] = c * 128 + (((hk * 2) ^ (c & 7)) << 4);
    }

    f32x4 acc[4][2];
    #pragma unroll
    for (int i = 0; i < 4; i++)
        #pragma unroll
        for (int j = 0; j < 2; j++) acc[i][j] = (f32x4){0.f, 0.f, 0.f, 0.f};

    for (int st = 0; st < 8; st++) {             // 8 K-steps of 128
        __syncthreads();                          // prev step's reads retired
        #pragma unroll
        for (int i = 0; i < 4; i++) async_cp16(gp[i] + st * 128, slab + ldo[i]);
        asm volatile("s_waitcnt vmcnt(0)" ::: "memory");
        __syncthreads();                          // whole tile staged

        i32x8 bv[2];
        #pragma unroll
        for (int nj = 0; nj < 2; nj++) {
            i32x4 lo = *(const i32x4*)(Bs + offB[nj]);
            i32x4 hi = *(const i32x4*)(Bs + (offB[nj] ^ 16));
            bv[nj] = __builtin_shufflevector(lo, hi, 0, 1, 2, 3, 4, 5, 6, 7);
        }
        #pragma unroll
        for (int mi = 0; mi < 4; mi++) {
            i32x4 lo = *(const i32x4*)(As + offA[mi]);
            i32x4 hi = *(const i32x4*)(As + (offA[mi] ^ 16));
            i32x8 av = __builtin_shufflevector(lo, hi, 0, 1, 2, 3, 4, 5, 6, 7);
            #pragma unroll
            for (int nj = 0; nj < 2; nj++)
                acc[mi][nj] = __builtin_amdgcn_mfma_scale_f32_16x16x128_f8f6f4(
                    av, bv[nj], acc[mi][nj], 0, 0, 0, 127, 0, 127);
        }
    }

    // epilogue: S = sq_i + sq_j - 2*sw*G', masked softplus, x2 off-diagonal
    __syncthreads();
    if (tid < 128)      { sqI[tid] = sq[it * 128 + tid]; tIs[tid] = tgt[it * 128 + tid]; }
    else if (tid < 256) { int u = tid - 128; sqJ[u] = sq[jt * 128 + u]; tJs[u] = tgt[jt * 128 + u]; }
    __syncthreads();

    float sw2 = 2.0f * scal[0];
    float sum = 0.f;
    bool diagTile = (it == jt);
    #pragma unroll
    for (int j = 0; j < 2; j++) {
        int col = wcol + j * 16 + (lane & 15);            // C/D: col = lane&15
        float sj = sqJ[col]; int tj = tJs[col];
        #pragma unroll
        for (int i = 0; i < 4; i++) {
            int rbase = wrow + i * 16 + (lane >> 4) * 4;  // C/D: row = quad*4+reg
            #pragma unroll
            for (int rr = 0; rr < 4; rr++) {
                int rowp = rbase + rr;
                float S = sqI[rowp] + sj - sw2 * acc[i][j][rr];
                float v;
                if (tIs[rowp] == tj) v = (diagTile && rowp == col) ? 0.f : softplus(-S);
                else                 v = softplus(S);
                sum += v;
            }
        }
    }
    float scale = (diagTile ? 1.f : 2.f) * (1.f / ((float)N_ROWS * (float)(N_ROWS - 1)));
    sum *= scale;
    for (int off = 32; off; off >>= 1) sum += __shfl_down(sum, off, 64);
    if (lane == 0) red[wave] = sum;
    __syncthreads();
    if (tid == 0) {
        float t = 0.f;
        #pragma unroll
        for (int wv = 0; wv < 8; wv++) t += red[wv];
        atomicAdd(loss, t);
    }
}

extern "C" void kernel_launch(void* const* d_in, const int* in_sizes, int n_in,
                              void* d_out, int out_size, void* d_ws, size_t ws_size,
                              hipStream_t stream) {
    const float* X  = (const float*)d_in[0];
    const int* tgt  = (const int*)d_in[1];
    float* out = (float*)d_out;
    char* ws = (char*)d_ws;
    const size_t MB = 1u << 20;

    float* w      = (float*)ws;                         // 4 KB
    float* sq     = (float*)(ws + 4096);                // 16 KB
    float* scal   = (float*)(ws + 24576);               // 4 B
    unsigned int* Xb8  = (unsigned int*)(ws + 1 * MB);  // 4 MB
    unsigned int* XWb8 = (unsigned int*)(ws + 5 * MB);  // 4 MB
    float* csumR  = (float*)(ws + 9 * MB);              // 256 KB
    float* csqR   = (float*)(ws + 9 * MB + 256 * 1024); // 256 KB

    k_cstats  <<<256,  256, 0, stream>>>(X, tgt, csumR, csqR);
    k_weights <<<8,    128, 0, stream>>>(tgt, csumR, csqR, w, scal, out);
    k_prep    <<<4096, 256, 0, stream>>>(X, w, scal, Xb8, XWb8, sq);
    k_gemm_loss<<<528, 512, 0, stream>>>((const unsigned char*)Xb8, (const unsigned char*)XWb8,
                                         sq, tgt, scal, out);
}

// Round 4
// 219.152 us; speedup vs baseline: 1.0326x; 1.0326x over previous
//
#include <hip/hip_runtime.h>
#include <stdint.h>

#define N_ROWS 4096
#define DIM    1024
#define NCLS   64
#define EPSV   0.1f

typedef __attribute__((ext_vector_type(4))) float f32x4;
typedef __attribute__((ext_vector_type(4))) int   i32x4;
typedef __attribute__((ext_vector_type(8))) int   i32x8;

__device__ __forceinline__ void async_cp16(const void* g, void* l) {
    __builtin_amdgcn_global_load_lds((const __attribute__((address_space(1))) void*)g,
                                     (__attribute__((address_space(3))) void*)l,
                                     16, 0, 0);
}

__device__ __forceinline__ float softplus(float x) {
    return fmaxf(x, 0.f) + __logf(1.f + __expf(-fabsf(x)));
}

// ---------------- K1: per-class sum/sqsum via row gather (unchanged) ---------
__global__ __launch_bounds__(256) void k_cstats(const float* __restrict__ X,
                                                const int* __restrict__ tgt,
                                                float* __restrict__ csumR,
                                                float* __restrict__ csqR) {
    __shared__ int rows[N_ROWS];
    __shared__ int nrows_s;
    int tid = threadIdx.x;
    int c = blockIdx.x >> 2, q = blockIdx.x & 3;
    if (tid == 0) nrows_s = 0;
    __syncthreads();
    for (int i = tid; i < N_ROWS; i += 256)
        if (tgt[i] == c) { int p = atomicAdd(&nrows_s, 1); rows[p] = i; }
    __syncthreads();
    int n = nrows_s;
    int d = q * 256 + tid;
    float s = 0.f, qq = 0.f;
    #pragma unroll 4
    for (int r = 0; r < n; r++) {
        float x = X[(size_t)rows[r] * DIM + d];
        s += x; qq += x * x;
    }
    csumR[c * DIM + d] = s;
    csqR [c * DIM + d] = qq;
}

// ---------------- K2: counts + weights + fp8 scale + zero loss (unchanged) ---
__global__ __launch_bounds__(128) void k_weights(const int* __restrict__ tgt,
                                                 const float* __restrict__ csumR,
                                                 const float* __restrict__ csqR,
                                                 float* __restrict__ w,
                                                 float* __restrict__ scal,
                                                 float* __restrict__ loss_out) {
    __shared__ int hist[NCLS];
    __shared__ float redw[2];
    int tid = threadIdx.x, b = blockIdx.x;
    if (tid < NCLS) hist[tid] = 0;
    __syncthreads();
    for (int i = tid; i < N_ROWS; i += 128) atomicAdd(&hist[tgt[i]], 1);
    __syncthreads();
    long long sp = 0, ss = 0;
    for (int c = 0; c < NCLS; c++) { long long cc = hist[c]; sp += cc * (cc - 1); ss += cc * cc; }
    float cnt_pos = (float)sp;
    float cnt_neg = (float)((long long)N_ROWS * N_ROWS - ss);
    int d = b * 128 + tid;
    float A = 0.f, X2 = 0.f, T = 0.f, SS = 0.f;
    #pragma unroll 8
    for (int c = 0; c < NCLS; c++) {
        float s = csumR[c * DIM + d];
        float q = csqR [c * DIM + d];
        A += (float)hist[c] * q; X2 += q; T += s; SS += s * s;
    }
    float posnum = 2.f * (A - SS);
    float negnum = 2.f * ((float)N_ROWS * X2 - A - T * T + SS);
    float wd = cnt_neg / (negnum + EPSV) - cnt_pos / (posnum + EPSV);
    w[d] = wd;
    float m = wd * wd;
    for (int off = 32; off; off >>= 1) m += __shfl_down(m, off, 64);
    int wv = tid >> 6, ln = tid & 63;
    if (ln == 0) redw[wv] = m;
    __syncthreads();
    if (b == 0 && tid == 0) {
        float ms = (redw[0] + redw[1]) / 128.f;
        scal[0] = exp2f(roundf(log2f(sqrtf(ms) + 1e-30f)));
        loss_out[0] = 0.0f;
    }
}

// ---------------- K3: xw, sq (fp32 exact), fp8 casts, PLAIN row-major --------
__global__ __launch_bounds__(256) void k_prep(const float* __restrict__ X,
                                              const float* __restrict__ w,
                                              const float* __restrict__ scal,
                                              unsigned int* __restrict__ Xb8,
                                              unsigned int* __restrict__ XWb8,
                                              float* __restrict__ sq) {
    int row = blockIdx.x, tid = threadIdx.x;
    float inv_sw = 1.0f / scal[0];
    float4 x  = ((const float4*)(X + (size_t)row * DIM))[tid];
    float4 ww = ((const float4*)w)[tid];
    float4 xw = make_float4(x.x * ww.x, x.y * ww.y, x.z * ww.z, x.w * ww.w);
    float p = x.x * xw.x + x.y * xw.y + x.z * xw.z + x.w * xw.w;
    unsigned ux = __builtin_amdgcn_cvt_pk_fp8_f32(x.x, x.y, 0, false);
    ux = __builtin_amdgcn_cvt_pk_fp8_f32(x.z, x.w, ux, true);
    unsigned uw = __builtin_amdgcn_cvt_pk_fp8_f32(xw.x * inv_sw, xw.y * inv_sw, 0, false);
    uw = __builtin_amdgcn_cvt_pk_fp8_f32(xw.z * inv_sw, xw.w * inv_sw, uw, true);
    int widx = row * 256 + tid;            // plain row-major fp8
    Xb8 [widx] = ux;
    XWb8[widx] = uw;
    for (int off = 32; off; off >>= 1) p += __shfl_down(p, off, 64);
    __shared__ float red[4];
    int wv = tid >> 6, ln = tid & 63;
    if (ln == 0) red[wv] = p;
    __syncthreads();
    if (tid == 0) sq[row] = red[0] + red[1] + red[2] + red[3];
}

// ---------------- K4: MX-fp8 (scale=1) MFMA gram + softplus + masked mean ----
// R3 geometry (8 waves, 64x32 wave tile, 4x2 16x16x128 frags) with TWO fixes:
// 1) __launch_bounds__(512, 2): min 2 waves/EU -> VGPR cap 256. R3's default
//    cap was 128 vs ~160 demand -> ~32 regs spilled in the K-loop = 213 MB
//    scratch writes. Demand fits 256 with ~90 regs headroom.
// 2) 2-phase double-buffered K-loop (Sec 5.5 minimal recipe): issue next
//    step's 4 global_load_lds BEFORE compute, single vmcnt(0)+barrier per
//    step. Stage latency hides under compute; WAR-safe (overwritten buffer
//    was retired at the previous barrier). Needed because >128 VGPR ->
//    1 block/CU, so cross-block overlap no longer hides the stage.
__global__ __launch_bounds__(512, 2) void k_gemm_loss(const unsigned char* __restrict__ Xb8,
                                                      const unsigned char* __restrict__ XWb8,
                                                      const float* __restrict__ sq,
                                                      const int* __restrict__ tgt,
                                                      const float* __restrict__ scal,
                                                      float* __restrict__ loss) {
    __shared__ __align__(16) unsigned char As[2][16384];  // 128 rows x 128 B, dbuf
    __shared__ __align__(16) unsigned char Bs[2][16384];
    __shared__ float sqI[128], sqJ[128];
    __shared__ int   tIs[128], tJs[128];
    __shared__ float red[8];

    int tid = threadIdx.x;
    int wave = tid >> 6, lane = tid & 63;

    // balanced triangular decode (32x32 tile grid, 528 tiles)
    int g = blockIdx.x & 7, s = blockIdx.x >> 3;
    int j0 = g, j1 = 15 - g, j2 = 16 + g;
    int n0 = j0 + 1, n1 = j1 + 1, n2 = j2 + 1;
    int jt, it;
    if      (s < n0)           { jt = j0; it = s; }
    else if (s < n0 + n1)      { jt = j1; it = s - n0; }
    else if (s < n0 + n1 + n2) { jt = j2; it = s - n0 - n1; }
    else                       { jt = 31 - g; it = s - n0 - n1 - n2; }

    // staging: waves 0-3 stage A, waves 4-7 stage B; 4 x 16 B per thread per
    // K-step; LDS linear dest, 16B-granule swizzle baked into global src:
    // phys granule = logical ^ (row & 7).
    bool isA = wave < 4;
    const unsigned char* srcb = (isA ? Xb8 : XWb8) + (size_t)((isA ? it : jt) * 128) * DIM;
    unsigned char* slab = isA ? &As[0][0] : &Bs[0][0];
    int ch = (wave & 3) * 64 + lane;
    const unsigned char* gp[4];
    int ldo[4];
    #pragma unroll
    for (int i = 0; i < 4; i++) {
        int r  = i * 32 + (ch >> 3);
        int pg = ch & 7;
        gp[i]  = srcb + (size_t)r * DIM + (size_t)((pg ^ (r & 7)) << 4);
        ldo[i] = i * 4096 + (wave & 3) * 1024;   // wave-uniform base
    }

    // fragment LDS byte offsets (step-invariant; add buf*16384 at use)
    int lr = lane & 15, hk = lane >> 4;
    int wrow = (wave >> 2) * 64, wcol = (wave & 3) * 32;
    int offA[4], offB[2];
    #pragma unroll
    for (int mi = 0; mi < 4; mi++) {
        int r = wrow + mi * 16 + lr;
        offA[mi] = r * 128 + (((hk * 2) ^ (r & 7)) << 4);
    }
    #pragma unroll
    for (int nj = 0; nj < 2; nj++) {
        int c = wcol + nj * 16 + lr;
        offB[nj] = c * 128 + (((hk * 2) ^ (c & 7)) << 4);
    }

    f32x4 acc[4][2];
    #pragma unroll
    for (int i = 0; i < 4; i++)
        #pragma unroll
        for (int j = 0; j < 2; j++) acc[i][j] = (f32x4){0.f, 0.f, 0.f, 0.f};

    // prologue: stage step 0 into buffer 0
    #pragma unroll
    for (int i = 0; i < 4; i++) async_cp16(gp[i], slab + ldo[i]);
    asm volatile("s_waitcnt vmcnt(0)" ::: "memory");
    __syncthreads();

    for (int st = 0; st < 8; st++) {
        int cur = st & 1;
        if (st < 7) {                            // issue next step into other buf
            #pragma unroll
            for (int i = 0; i < 4; i++)
                async_cp16(gp[i] + (size_t)(st + 1) * 128,
                           slab + ((cur ^ 1) << 14) + ldo[i]);
        }
        const unsigned char* Ab = As[cur];
        const unsigned char* Bb = Bs[cur];
        i32x8 bv[2];
        #pragma unroll
        for (int nj = 0; nj < 2; nj++) {
            i32x4 lo = *(const i32x4*)(Bb + offB[nj]);
            i32x4 hi = *(const i32x4*)(Bb + (offB[nj] ^ 16));
            bv[nj] = __builtin_shufflevector(lo, hi, 0, 1, 2, 3, 4, 5, 6, 7);
        }
        #pragma unroll
        for (int mi = 0; mi < 4; mi++) {
            i32x4 lo = *(const i32x4*)(Ab + offA[mi]);
            i32x4 hi = *(const i32x4*)(Ab + (offA[mi] ^ 16));
            i32x8 av = __builtin_shufflevector(lo, hi, 0, 1, 2, 3, 4, 5, 6, 7);
            #pragma unroll
            for (int nj = 0; nj < 2; nj++)
                acc[mi][nj] = __builtin_amdgcn_mfma_scale_f32_16x16x128_f8f6f4(
                    av, bv[nj], acc[mi][nj], 0, 0, 0, 127, 0, 127);
        }
        asm volatile("s_waitcnt vmcnt(0)" ::: "memory");  // next-buf writes landed
        __syncthreads();                                  // all waves done reading cur
    }

    // epilogue: S = sq_i + sq_j - 2*sw*G', masked softplus, x2 off-diagonal
    if (tid < 128)      { sqI[tid] = sq[it * 128 + tid]; tIs[tid] = tgt[it * 128 + tid]; }
    else if (tid < 256) { int u = tid - 128; sqJ[u] = sq[jt * 128 + u]; tJs[u] = tgt[jt * 128 + u]; }
    __syncthreads();

    float sw2 = 2.0f * scal[0];
    float sum = 0.f;
    bool diagTile = (it == jt);
    #pragma unroll
    for (int j = 0; j < 2; j++) {
        int col = wcol + j * 16 + (lane & 15);            // C/D: col = lane&15
        float sj = sqJ[col]; int tj = tJs[col];
        #pragma unroll
        for (int i = 0; i < 4; i++) {
            int rbase = wrow + i * 16 + (lane >> 4) * 4;  // C/D: row = quad*4+reg
            #pragma unroll
            for (int rr = 0; rr < 4; rr++) {
                int rowp = rbase + rr;
                float S = sqI[rowp] + sj - sw2 * acc[i][j][rr];
                float v;
                if (tIs[rowp] == tj) v = (diagTile && rowp == col) ? 0.f : softplus(-S);
                else                 v = softplus(S);
                sum += v;
            }
        }
    }
    float scale = (diagTile ? 1.f : 2.f) * (1.f / ((float)N_ROWS * (float)(N_ROWS - 1)));
    sum *= scale;
    for (int off = 32; off; off >>= 1) sum += __shfl_down(sum, off, 64);
    if (lane == 0) red[wave] = sum;
    __syncthreads();
    if (tid == 0) {
        float t = 0.f;
        #pragma unroll
        for (int wv = 0; wv < 8; wv++) t += red[wv];
        atomicAdd(loss, t);
    }
}

extern "C" void kernel_launch(void* const* d_in, const int* in_sizes, int n_in,
                              void* d_out, int out_size, void* d_ws, size_t ws_size,
                              hipStream_t stream) {
    const float* X  = (const float*)d_in[0];
    const int* tgt  = (const int*)d_in[1];
    float* out = (float*)d_out;
    char* ws = (char*)d_ws;
    const size_t MB = 1u << 20;

    float* w      = (float*)ws;                         // 4 KB
    float* sq     = (float*)(ws + 4096);                // 16 KB
    float* scal   = (float*)(ws + 24576);               // 4 B
    unsigned int* Xb8  = (unsigned int*)(ws + 1 * MB);  // 4 MB
    unsigned int* XWb8 = (unsigned int*)(ws + 5 * MB);  // 4 MB
    float* csumR  = (float*)(ws + 9 * MB);              // 256 KB
    float* csqR   = (float*)(ws + 9 * MB + 256 * 1024); // 256 KB

    k_cstats  <<<256,  256, 0, stream>>>(X, tgt, csumR, csqR);
    k_weights <<<8,    128, 0, stream>>>(tgt, csumR, csqR, w, scal, out);
    k_prep    <<<4096, 256, 0, stream>>>(X, w, scal, Xb8, XWb8, sq);
    k_gemm_loss<<<528, 512, 0, stream>>>((const unsigned char*)Xb8, (const unsigned char*)XWb8,
                                         sq, tgt, scal, out);
}

// Round 5
// 123.132 us; speedup vs baseline: 1.8378x; 1.7798x over previous
//
#include <hip/hip_runtime.h>
#include <stdint.h>

#define N_ROWS 4096
#define DIM    1024
#define NCLS   64
#define EPSV   0.1f

typedef __attribute__((ext_vector_type(4))) float f32x4;
typedef __attribute__((ext_vector_type(4))) int   i32x4;
typedef __attribute__((ext_vector_type(8))) int   i32x8;

__device__ __forceinline__ void async_cp16(const void* g, void* l) {
    __builtin_amdgcn_global_load_lds((const __attribute__((address_space(1))) void*)g,
                                     (__attribute__((address_space(3))) void*)l,
                                     16, 0, 0);
}

__device__ __forceinline__ float softplus(float x) {
    return fmaxf(x, 0.f) + __logf(1.f + __expf(-fabsf(x)));
}

// ---------------- K1: per-class sum/sqsum via row gather (unchanged) ---------
__global__ __launch_bounds__(256) void k_cstats(const float* __restrict__ X,
                                                const int* __restrict__ tgt,
                                                float* __restrict__ csumR,
                                                float* __restrict__ csqR) {
    __shared__ int rows[N_ROWS];
    __shared__ int nrows_s;
    int tid = threadIdx.x;
    int c = blockIdx.x >> 2, q = blockIdx.x & 3;
    if (tid == 0) nrows_s = 0;
    __syncthreads();
    for (int i = tid; i < N_ROWS; i += 256)
        if (tgt[i] == c) { int p = atomicAdd(&nrows_s, 1); rows[p] = i; }
    __syncthreads();
    int n = nrows_s;
    int d = q * 256 + tid;
    float s = 0.f, qq = 0.f;
    #pragma unroll 4
    for (int r = 0; r < n; r++) {
        float x = X[(size_t)rows[r] * DIM + d];
        s += x; qq += x * x;
    }
    csumR[c * DIM + d] = s;
    csqR [c * DIM + d] = qq;
}

// ---------------- K2: counts + weights + fp8 scale + zero loss (unchanged) ---
__global__ __launch_bounds__(128) void k_weights(const int* __restrict__ tgt,
                                                 const float* __restrict__ csumR,
                                                 const float* __restrict__ csqR,
                                                 float* __restrict__ w,
                                                 float* __restrict__ scal,
                                                 float* __restrict__ loss_out) {
    __shared__ int hist[NCLS];
    __shared__ float redw[2];
    int tid = threadIdx.x, b = blockIdx.x;
    if (tid < NCLS) hist[tid] = 0;
    __syncthreads();
    for (int i = tid; i < N_ROWS; i += 128) atomicAdd(&hist[tgt[i]], 1);
    __syncthreads();
    long long sp = 0, ss = 0;
    for (int c = 0; c < NCLS; c++) { long long cc = hist[c]; sp += cc * (cc - 1); ss += cc * cc; }
    float cnt_pos = (float)sp;
    float cnt_neg = (float)((long long)N_ROWS * N_ROWS - ss);
    int d = b * 128 + tid;
    float A = 0.f, X2 = 0.f, T = 0.f, SS = 0.f;
    #pragma unroll 8
    for (int c = 0; c < NCLS; c++) {
        float s = csumR[c * DIM + d];
        float q = csqR [c * DIM + d];
        A += (float)hist[c] * q; X2 += q; T += s; SS += s * s;
    }
    float posnum = 2.f * (A - SS);
    float negnum = 2.f * ((float)N_ROWS * X2 - A - T * T + SS);
    float wd = cnt_neg / (negnum + EPSV) - cnt_pos / (posnum + EPSV);
    w[d] = wd;
    float m = wd * wd;
    for (int off = 32; off; off >>= 1) m += __shfl_down(m, off, 64);
    int wv = tid >> 6, ln = tid & 63;
    if (ln == 0) redw[wv] = m;
    __syncthreads();
    if (b == 0 && tid == 0) {
        float ms = (redw[0] + redw[1]) / 128.f;
        scal[0] = exp2f(roundf(log2f(sqrtf(ms) + 1e-30f)));
        loss_out[0] = 0.0f;
    }
}

// ---------------- K3: xw, sq (fp32 exact), fp8 casts, PLAIN row-major --------
__global__ __launch_bounds__(256) void k_prep(const float* __restrict__ X,
                                              const float* __restrict__ w,
                                              const float* __restrict__ scal,
                                              unsigned int* __restrict__ Xb8,
                                              unsigned int* __restrict__ XWb8,
                                              float* __restrict__ sq) {
    int row = blockIdx.x, tid = threadIdx.x;
    float inv_sw = 1.0f / scal[0];
    float4 x  = ((const float4*)(X + (size_t)row * DIM))[tid];
    float4 ww = ((const float4*)w)[tid];
    float4 xw = make_float4(x.x * ww.x, x.y * ww.y, x.z * ww.z, x.w * ww.w);
    float p = x.x * xw.x + x.y * xw.y + x.z * xw.z + x.w * xw.w;
    unsigned ux = __builtin_amdgcn_cvt_pk_fp8_f32(x.x, x.y, 0, false);
    ux = __builtin_amdgcn_cvt_pk_fp8_f32(x.z, x.w, ux, true);
    unsigned uw = __builtin_amdgcn_cvt_pk_fp8_f32(xw.x * inv_sw, xw.y * inv_sw, 0, false);
    uw = __builtin_amdgcn_cvt_pk_fp8_f32(xw.z * inv_sw, xw.w * inv_sw, uw, true);
    int widx = row * 256 + tid;            // plain row-major fp8
    Xb8 [widx] = ux;
    XWb8[widx] = uw;
    for (int off = 32; off; off >>= 1) p += __shfl_down(p, off, 64);
    __shared__ float red[4];
    int wv = tid >> 6, ln = tid & 63;
    if (ln == 0) red[wv] = p;
    __syncthreads();
    if (tid == 0) sq[row] = red[0] + red[1] + red[2] + red[3];
}

// ---------------- K4: MX-fp8 (scale=1) MFMA gram + softplus + masked mean ----
// R4 post-mortem: hipcc pins 512-thread kernels at 128 arch VGPRs regardless
// of launch_bounds min-waves; the i32x8 shufflevector operand build (lo+hi+
// result = 16 transient regs x 6 fragments) pushed demand to ~200 -> 25
// dwords respilled per K-step = 213 MB scratch (R3 == R4 byte-identical).
// FIX: make each fragment's 32 B contiguous + K-ordered in LDS so operands
// load as direct i32x8 (2x ds_read_b128 into the MFMA tuple, zero temps).
// Requires a PAIR-preserving swizzle: phys_32B_pair = hk ^ (row&3) (bit0 of
// the 16B granule untouched -> K order kept). Read spread drops 8->4-way
// (~2x LDS-read penalty, ~770 cy/step/block) -- cheap vs 213 MB of scratch.
// Demand now ~ acc32 + bv16 + av8 + ptrs/addr ~30 = ~110 <= 128 cap.
// Dbuf kept; buffer selection made compile-time static (rule #20 hygiene).
__global__ __launch_bounds__(512) void k_gemm_loss(const unsigned char* __restrict__ Xb8,
                                                   const unsigned char* __restrict__ XWb8,
                                                   const float* __restrict__ sq,
                                                   const int* __restrict__ tgt,
                                                   const float* __restrict__ scal,
                                                   float* __restrict__ loss) {
    __shared__ __align__(64) unsigned char As[2][16384];  // 128 rows x 128 B, dbuf
    __shared__ __align__(64) unsigned char Bs[2][16384];
    __shared__ float sqI[128], sqJ[128];
    __shared__ int   tIs[128], tJs[128];
    __shared__ float red[8];

    int tid = threadIdx.x;
    int wave = tid >> 6, lane = tid & 63;

    // balanced triangular decode (32x32 tile grid, 528 tiles)
    int g = blockIdx.x & 7, s = blockIdx.x >> 3;
    int j0 = g, j1 = 15 - g, j2 = 16 + g;
    int n0 = j0 + 1, n1 = j1 + 1, n2 = j2 + 1;
    int jt, it;
    if      (s < n0)           { jt = j0; it = s; }
    else if (s < n0 + n1)      { jt = j1; it = s - n0; }
    else if (s < n0 + n1 + n2) { jt = j2; it = s - n0 - n1; }
    else                       { jt = 31 - g; it = s - n0 - n1 - n2; }

    // staging: waves 0-3 stage A, waves 4-7 stage B; 4 x 16 B per thread per
    // K-step; LDS linear dest. Pair-preserving swizzle baked into global src:
    // LDS phys granule p of row r holds logical granule
    //   l = (((p>>1) ^ (r&3)) << 1) | (p&1)
    bool isA = wave < 4;
    const unsigned char* srcb = (isA ? Xb8 : XWb8) + (size_t)((isA ? it : jt) * 128) * DIM;
    unsigned char* slab = isA ? &As[0][0] : &Bs[0][0];
    int ch = (wave & 3) * 64 + lane;
    const unsigned char* gp[4];
    int ldo[4];
    #pragma unroll
    for (int i = 0; i < 4; i++) {
        int r  = i * 32 + (ch >> 3);
        int p  = ch & 7;
        int lg = ((((p >> 1) ^ (r & 3)) << 1) | (p & 1));
        gp[i]  = srcb + (size_t)r * DIM + (size_t)(lg << 4);
        ldo[i] = i * 4096 + (wave & 3) * 1024;   // wave-uniform base
    }

    // fragment LDS byte offsets: 32B-aligned contiguous pair per fragment
    int lr = lane & 15, hk = lane >> 4;
    int wrow = (wave >> 2) * 64, wcol = (wave & 3) * 32;
    int offA[4], offB[2];
    #pragma unroll
    for (int mi = 0; mi < 4; mi++) {
        int r = wrow + mi * 16 + lr;
        offA[mi] = r * 128 + ((hk ^ (r & 3)) << 5);
    }
    #pragma unroll
    for (int nj = 0; nj < 2; nj++) {
        int c = wcol + nj * 16 + lr;
        offB[nj] = c * 128 + ((hk ^ (c & 3)) << 5);
    }

    f32x4 acc[4][2];
    #pragma unroll
    for (int i = 0; i < 4; i++)
        #pragma unroll
        for (int j = 0; j < 2; j++) acc[i][j] = (f32x4){0.f, 0.f, 0.f, 0.f};

    auto compute = [&](const unsigned char* __restrict__ Ab,
                       const unsigned char* __restrict__ Bb) {
        i32x8 bv[2];
        #pragma unroll
        for (int nj = 0; nj < 2; nj++)
            bv[nj] = *(const i32x8*)(Bb + offB[nj]);
        #pragma unroll
        for (int mi = 0; mi < 4; mi++) {
            i32x8 av = *(const i32x8*)(Ab + offA[mi]);
            #pragma unroll
            for (int nj = 0; nj < 2; nj++)
                acc[mi][nj] = __builtin_amdgcn_mfma_scale_f32_16x16x128_f8f6f4(
                    av, bv[nj], acc[mi][nj], 0, 0, 0, 127, 0, 127);
        }
    };

    // prologue: stage step 0 into buffer 0
    #pragma unroll
    for (int i = 0; i < 4; i++) async_cp16(gp[i], slab + ldo[i]);
    asm volatile("s_waitcnt vmcnt(0)" ::: "memory");
    __syncthreads();

    #pragma unroll 1
    for (int st = 0; st < 8; st += 2) {
        // even step: compute buf0, prefetch st+1 -> buf1
        #pragma unroll
        for (int i = 0; i < 4; i++)
            async_cp16(gp[i] + (size_t)(st + 1) * 128, slab + 16384 + ldo[i]);
        compute(As[0], Bs[0]);
        asm volatile("s_waitcnt vmcnt(0)" ::: "memory");
        __syncthreads();
        // odd step: compute buf1, prefetch st+2 -> buf0
        if (st + 2 < 8) {
            #pragma unroll
            for (int i = 0; i < 4; i++)
                async_cp16(gp[i] + (size_t)(st + 2) * 128, slab + ldo[i]);
        }
        compute(As[1], Bs[1]);
        asm volatile("s_waitcnt vmcnt(0)" ::: "memory");
        __syncthreads();
    }

    // epilogue: S = sq_i + sq_j - 2*sw*G', masked softplus, x2 off-diagonal
    if (tid < 128)      { sqI[tid] = sq[it * 128 + tid]; tIs[tid] = tgt[it * 128 + tid]; }
    else if (tid < 256) { int u = tid - 128; sqJ[u] = sq[jt * 128 + u]; tJs[u] = tgt[jt * 128 + u]; }
    __syncthreads();

    float sw2 = 2.0f * scal[0];
    float sum = 0.f;
    bool diagTile = (it == jt);
    #pragma unroll
    for (int j = 0; j < 2; j++) {
        int col = wcol + j * 16 + (lane & 15);            // C/D: col = lane&15
        float sj = sqJ[col]; int tj = tJs[col];
        #pragma unroll
        for (int i = 0; i < 4; i++) {
            int rbase = wrow + i * 16 + (lane >> 4) * 4;  // C/D: row = quad*4+reg
            #pragma unroll
            for (int rr = 0; rr < 4; rr++) {
                int rowp = rbase + rr;
                float S = sqI[rowp] + sj - sw2 * acc[i][j][rr];
                float v;
                if (tIs[rowp] == tj) v = (diagTile && rowp == col) ? 0.f : softplus(-S);
                else                 v = softplus(S);
                sum += v;
            }
        }
    }
    float scale = (diagTile ? 1.f : 2.f) * (1.f / ((float)N_ROWS * (float)(N_ROWS - 1)));
    sum *= scale;
    for (int off = 32; off; off >>= 1) sum += __shfl_down(sum, off, 64);
    if (lane == 0) red[wave] = sum;
    __syncthreads();
    if (tid == 0) {
        float t = 0.f;
        #pragma unroll
        for (int wv = 0; wv < 8; wv++) t += red[wv];
        atomicAdd(loss, t);
    }
}

extern "C" void kernel_launch(void* const* d_in, const int* in_sizes, int n_in,
                              void* d_out, int out_size, void* d_ws, size_t ws_size,
                              hipStream_t stream) {
    const float* X  = (const float*)d_in[0];
    const int* tgt  = (const int*)d_in[1];
    float* out = (float*)d_out;
    char* ws = (char*)d_ws;
    const size_t MB = 1u << 20;

    float* w      = (float*)ws;                         // 4 KB
    float* sq     = (float*)(ws + 4096);                // 16 KB
    float* scal   = (float*)(ws + 24576);               // 4 B
    unsigned int* Xb8  = (unsigned int*)(ws + 1 * MB);  // 4 MB
    unsigned int* XWb8 = (unsigned int*)(ws + 5 * MB);  // 4 MB
    float* csumR  = (float*)(ws + 9 * MB);              // 256 KB
    float* csqR   = (float*)(ws + 9 * MB + 256 * 1024); // 256 KB

    k_cstats  <<<256,  256, 0, stream>>>(X, tgt, csumR, csqR);
    k_weights <<<8,    128, 0, stream>>>(tgt, csumR, csqR, w, scal, out);
    k_prep    <<<4096, 256, 0, stream>>>(X, w, scal, Xb8, XWb8, sq);
    k_gemm_loss<<<528, 512, 0, stream>>>((const unsigned char*)Xb8, (const unsigned char*)XWb8,
                                         sq, tgt, scal, out);
}